// Round 11
// baseline (95.274 us; speedup 1.0000x reference)
//
#include <hip/hip_runtime.h>
#include <math.h>

// Rotated 3D IoU loss — round 11 = R10 compute core + FUSED reduction
// (ticket / last-block-done), eliminating the second kernel launch.
// Cross-XCD safety (G16): partials stored with agent-scope RELEASE atomic
// stores, ticket via agent-scope ACQ_REL fetch_add, last block reads with
// agent-scope ACQUIRE loads — per-XCD L2s are not coherent, so all
// inter-block traffic goes through device-scope atomics.
// Semantics = literal emulation of the reference (incl. its u = -den_u/num
// "backward-extension" intersection mask — verified numerically in R6).

#define RCP(x) __builtin_amdgcn_rcpf(x)

__global__ __launch_bounds__(256, 3) void riou_loss_kernel(
    const float* __restrict__ pred, const float* __restrict__ tgt,
    const float* __restrict__ wgt, unsigned* __restrict__ cnt,
    float* __restrict__ part, float* __restrict__ out, int n, int nb)
{
    int i = blockIdx.x * 256 + threadIdx.x;
    float loss = 0.0f;
    if (i < n) {
        const float* pp = pred + 7 * i;
        const float* qq = tgt + 7 * i;
        float wg = wgt[i];
        float p0 = pp[0], p1 = pp[1], p2 = pp[2], p3 = pp[3], p4 = pp[4], p5 = pp[5], p6 = pp[6];
        float q0 = qq[0], q1 = qq[1], q2 = qq[2], q3 = qq[3], q4 = qq[4], q5 = qq[5], q6 = qq[6];

        // ---- decode_fcos_obb (loc = 0) ----
        float w1 = p0 + p3, l1 = p1 + p4, h1 = p2 + p5;
        float oz1 = (p5 - p2) * 0.5f;
        float ox1 = (p3 - p0) * 0.5f, oy1 = (p4 - p1) * 0.5f;
        float sA = __sinf(p6), cA = __cosf(p6);
        float cx1 = ox1 * cA - oy1 * sA, cy1 = ox1 * sA + oy1 * cA;

        float w2 = q0 + q3, l2 = q1 + q4, h2 = q2 + q5;
        float oz2 = (q5 - q2) * 0.5f;
        float ox2 = (q3 - q0) * 0.5f, oy2 = (q4 - q1) * 0.5f;
        float sB = __sinf(q6), cB = __cosf(q6);
        float cx2 = ox2 * cB - oy2 * sB, cy2 = ox2 * sB + oy2 * cB;

        // epilogue scalars folded early
        float vol1 = w1 * l1 * h1, vol2 = w2 * l2 * h2;
        float zo = fmaxf(fminf(oz1 + h1 * 0.5f, oz2 + h2 * 0.5f) -
                         fmaxf(oz1 - h1 * 0.5f, oz2 - h2 * 0.5f), 0.0f);

        // ---- corners: signs (+,+),(-,+),(-,-),(+,-) of (w/2, l/2), rotated ----
        float hw1 = 0.5f * w1, hl1 = 0.5f * l1;
        float c1x0 =  hw1 * cA - hl1 * sA + cx1, c1y0 =  hw1 * sA + hl1 * cA + cy1;
        float c1x1 = -hw1 * cA - hl1 * sA + cx1, c1y1 = -hw1 * sA + hl1 * cA + cy1;
        float c1x2 = -hw1 * cA + hl1 * sA + cx1, c1y2 = -hw1 * sA - hl1 * cA + cy1;
        float c1x3 =  hw1 * cA + hl1 * sA + cx1, c1y3 =  hw1 * sA - hl1 * cA + cy1;
        float hw2 = 0.5f * w2, hl2 = 0.5f * l2;
        float c2x0 =  hw2 * cB - hl2 * sB + cx2, c2y0 =  hw2 * sB + hl2 * cB + cy2;
        float c2x1 = -hw2 * cB - hl2 * sB + cx2, c2y1 = -hw2 * sB + hl2 * cB + cy2;
        float c2x2 = -hw2 * cB + hl2 * sB + cx2, c2y2 = -hw2 * sB - hl2 * cB + cy2;
        float c2x3 =  hw2 * cB + hl2 * sB + cx2, c2y3 =  hw2 * sB - hl2 * cB + cy2;

        float sumx = 0.0f, sumy = 0.0f;
        int nv = 0;
#define ACC(M, X, Y) { sumx += (M) ? (X) : 0.0f; sumy += (M) ? (Y) : 0.0f; nv += (M) ? 1 : 0; }

        // ---- point-in-box masks; x in (-tol,1+tol) <=> |x-0.5| < 0.5+tol ----
        const float HT = 0.5f + 1e-6f;
        float abxB = c2x1 - c2x0, abyB = c2y1 - c2y0;
        float adxB = c2x3 - c2x0, adyB = c2y3 - c2y0;
        float rabB = RCP(abxB * abxB + abyB * abyB);
        float radB = RCP(adxB * adxB + adyB * adyB);
#define PIB_B(MX, MY, M) { float amx = (MX) - c2x0, amy = (MY) - c2y0; \
        float pab = (abxB * amx + abyB * amy) * rabB; \
        float pdd = (adxB * amx + adyB * amy) * radB; \
        M = (fabsf(pab - 0.5f) < HT) & (fabsf(pdd - 0.5f) < HT); }
        bool mA0, mA1, mA2, mA3;
        PIB_B(c1x0, c1y0, mA0) PIB_B(c1x1, c1y1, mA1)
        PIB_B(c1x2, c1y2, mA2) PIB_B(c1x3, c1y3, mA3)
        ACC(mA0, c1x0, c1y0) ACC(mA1, c1x1, c1y1) ACC(mA2, c1x2, c1y2) ACC(mA3, c1x3, c1y3)
        float abxA = c1x1 - c1x0, abyA = c1y1 - c1y0;
        float adxA = c1x3 - c1x0, adyA = c1y3 - c1y0;
        float rabA = RCP(abxA * abxA + abyA * abyA);
        float radA = RCP(adxA * adxA + adyA * adyA);
#define PIB_A(MX, MY, M) { float amx = (MX) - c1x0, amy = (MY) - c1y0; \
        float pab = (abxA * amx + abyA * amy) * rabA; \
        float pdd = (adxA * amx + adyA * amy) * radA; \
        M = (fabsf(pab - 0.5f) < HT) & (fabsf(pdd - 0.5f) < HT); }
        bool mB0, mB1, mB2, mB3;
        PIB_A(c2x0, c2y0, mB0) PIB_A(c2x1, c2y1, mB1)
        PIB_A(c2x2, c2y2, mB2) PIB_A(c2x3, c2y3, mB3)
        ACC(mB0, c2x0, c2y0) ACC(mB1, c2x1, c2y1) ACC(mB2, c2x2, c2y2) ACC(mB3, c2x3, c2y3)

        // ---- edge-edge "intersections", reference's exact (buggy-u) mask ----
#define ISECT(X1, Y1, X2, Y2, X3, Y3, X4, Y4, PX, PY, M) { \
        float ex = (X2) - (X1), ey = (Y2) - (Y1); \
        float fx = (X4) - (X3), fy = (Y4) - (Y3); \
        float gx = (X1) - (X3), gy = (Y1) - (Y3); \
        float num = fy * ex - fx * ey; \
        float dt_ = fx * gy - fy * gx; \
        float du_ = ex * gy - ey * gx; \
        float rr = RCP(num); \
        float tt = dt_ * rr, uu = -du_ * rr; \
        M = (fabsf(tt - 0.5f) < 0.5f) & (fabsf(uu - 0.5f) < 0.5f); \
        PX = (X1) + tt * ex; PY = (Y1) + tt * ey; }
#define SITEM(PX, PY, M, OX0, OY0, OX1, OY1, CNT) { \
        bool tk0 = (M) && ((CNT) == 0); bool tk1 = (M) && ((CNT) == 1); \
        OX0 = tk0 ? (PX) : OX0; OY0 = tk0 ? (PY) : OY0; \
        OX1 = tk1 ? (PX) : OX1; OY1 = tk1 ? (PY) : OY1; \
        CNT += (M) ? 1 : 0; }
#define EDGE_GROUP(X1, Y1, X2, Y2, EX0, EY0, EX1, EY1) { \
        int gc = 0; float px, py; bool mm; \
        ISECT(X1, Y1, X2, Y2, c2x0, c2y0, c2x1, c2y1, px, py, mm) \
        ACC(mm, px, py) SITEM(px, py, mm, EX0, EY0, EX1, EY1, gc) \
        ISECT(X1, Y1, X2, Y2, c2x1, c2y1, c2x2, c2y2, px, py, mm) \
        ACC(mm, px, py) SITEM(px, py, mm, EX0, EY0, EX1, EY1, gc) \
        ISECT(X1, Y1, X2, Y2, c2x2, c2y2, c2x3, c2y3, px, py, mm) \
        ACC(mm, px, py) SITEM(px, py, mm, EX0, EY0, EX1, EY1, gc) \
        ISECT(X1, Y1, X2, Y2, c2x3, c2y3, c2x0, c2y0, px, py, mm) \
        ACC(mm, px, py) SITEM(px, py, mm, EX0, EY0, EX1, EY1, gc) }

        float vx8 = 0.f, vy8 = 0.f, vx9 = 0.f, vy9 = 0.f;
        float vx10 = 0.f, vy10 = 0.f, vx11 = 0.f, vy11 = 0.f;
        float vx12 = 0.f, vy12 = 0.f, vx13 = 0.f, vy13 = 0.f;
        float vx14 = 0.f, vy14 = 0.f, vx15 = 0.f, vy15 = 0.f;
        int nv8_before = nv;
        EDGE_GROUP(c1x0, c1y0, c1x1, c1y1, vx8, vy8, vx9, vy9)
        int nv10_before = nv;
        EDGE_GROUP(c1x1, c1y1, c1x2, c1y2, vx10, vy10, vx11, vy11)
        int nv12_before = nv;
        EDGE_GROUP(c1x2, c1y2, c1x3, c1y3, vx12, vy12, vx13, vy13)
        int nv14_before = nv;
        EDGE_GROUP(c1x3, c1y3, c1x0, c1y0, vx14, vy14, vx15, vy15)
        bool m8  = (nv10_before - nv8_before) > 0, m9  = (nv10_before - nv8_before) > 1;
        bool m10 = (nv12_before - nv10_before) > 0, m11 = (nv12_before - nv10_before) > 1;
        bool m12 = (nv14_before - nv12_before) > 0, m13 = (nv14_before - nv12_before) > 1;
        bool m14 = (nv - nv14_before) > 0,          m15 = (nv - nv14_before) > 1;

        float vx0 = c1x0, vy0 = c1y0, vx1 = c1x1, vy1 = c1y1;
        float vx2 = c1x2, vy2 = c1y2, vx3 = c1x3, vy3 = c1y3;
        float vx4 = c2x0, vy4 = c2y0, vx5 = c2x1, vy5 = c2y1;
        float vx6 = c2x2, vy6 = c2y2, vx7 = c2x3, vy7 = c2y3;
        bool m0 = mA0, m1 = mA1, m2 = mA2, m3 = mA3;
        bool m4 = mB0, m5 = mB1, m6 = mB2, m7 = mB3;

        // ---- center; branch-free diamond key (monotone in atan2, verified) ----
        float inv_nv = RCP(fmaxf((float)nv, 1.0f));
        float mx_ = sumx * inv_nv, my_ = sumy * inv_nv;
        float ang0, ang1, ang2, ang3, ang4, ang5, ang6, ang7;
        float ang8, ang9, ang10, ang11, ang12, ang13, ang14, ang15;
        unsigned pk0, pk1, pk2, pk3, pk4, pk5, pk6, pk7;
        unsigned pk8, pk9, pk10, pk11, pk12, pk13, pk14, pk15;
#define ANGPACK(K) { float xc = vx##K - mx_, yc = vy##K - my_; \
        float tt = xc * RCP(fmaxf(fabsf(xc) + fabsf(yc), 1e-38f)); \
        float key = copysignf(1.0f - tt, yc); \
        ang##K = m##K ? key : 1e6f; \
        pk##K = (__float_as_uint(xc) & 0xFFFF0000u) | (__float_as_uint(yc) >> 16); }
        ANGPACK(0) ANGPACK(1) ANGPACK(2) ANGPACK(3)
        ANGPACK(4) ANGPACK(5) ANGPACK(6) ANGPACK(7)
        ANGPACK(8) ANGPACK(9) ANGPACK(10) ANGPACK(11)
        ANGPACK(12) ANGPACK(13) ANGPACK(14) ANGPACK(15)

        // ---- Batcher odd-even mergesort, 16 elems, 63 CEs; 5 inst/CE ----
#define CE(A, B) { bool sw = ang##A > ang##B; \
        float mn = fminf(ang##A, ang##B), mx2 = fmaxf(ang##A, ang##B); \
        ang##A = mn; ang##B = mx2; \
        unsigned ta = pk##A; pk##A = sw ? pk##B : pk##A; pk##B = sw ? ta : pk##B; }
        CE(0,1) CE(2,3) CE(4,5) CE(6,7) CE(8,9) CE(10,11) CE(12,13) CE(14,15)
        CE(0,2) CE(1,3) CE(4,6) CE(5,7) CE(8,10) CE(9,11) CE(12,14) CE(13,15)
        CE(1,2) CE(5,6) CE(9,10) CE(13,14)
        CE(0,4) CE(1,5) CE(2,6) CE(3,7) CE(8,12) CE(9,13) CE(10,14) CE(11,15)
        CE(2,4) CE(3,5) CE(10,12) CE(11,13)
        CE(1,2) CE(3,4) CE(5,6) CE(9,10) CE(11,12) CE(13,14)
        CE(0,8) CE(1,9) CE(2,10) CE(3,11) CE(4,12) CE(5,13) CE(6,14) CE(7,15)
        CE(4,8) CE(5,9) CE(6,10) CE(7,11)
        CE(2,4) CE(3,5) CE(6,8) CE(7,9) CE(10,12) CE(11,13)
        CE(1,2) CE(3,4) CE(5,6) CE(7,8) CE(9,10) CE(11,12) CE(13,14)

        // ---- ref padding: invalid slots (key 1e6) sorted last ----
#define PAD(K) { pk##K = (ang##K > 5e5f) ? pk0 : pk##K; }
        PAD(1) PAD(2) PAD(3) PAD(4) PAD(5) PAD(6) PAD(7) PAD(8)
        PAD(9) PAD(10) PAD(11) PAD(12) PAD(13) PAD(14) PAD(15)

        // ---- unpack + cyclic shoelace ----
#define UPX(K) float ux##K = __uint_as_float(pk##K & 0xFFFF0000u); \
               float uy##K = __uint_as_float(pk##K << 16);
        UPX(0) UPX(1) UPX(2) UPX(3) UPX(4) UPX(5) UPX(6) UPX(7)
        UPX(8) UPX(9) UPX(10) UPX(11) UPX(12) UPX(13) UPX(14) UPX(15)
        float cs = 0.0f;
#define SHOE(A, B) cs += ux##A * uy##B - uy##A * ux##B;
        SHOE(0,1) SHOE(1,2) SHOE(2,3) SHOE(3,4) SHOE(4,5) SHOE(5,6) SHOE(6,7) SHOE(7,8)
        SHOE(8,9) SHOE(9,10) SHOE(10,11) SHOE(11,12) SHOE(12,13) SHOE(13,14) SHOE(14,15) SHOE(15,0)
        float inter = 0.5f * fabsf(cs);

        // ---- loss (iou2d*u2 cancels u2 -> inter3d = inter*zo) ----
        float inter3d = inter * zo;
        float u3d = vol1 + vol2 - inter3d;
        float iouf = (inter3d + 1.0f) * RCP(u3d + 1.0f);
        loss = -__logf(iouf) * wg;
    }

    // ---- block reduction -> per-block partial (agent-scope release) ----
#pragma unroll
    for (int off = 32; off > 0; off >>= 1)
        loss += __shfl_down(loss, off, 64);
    __shared__ float wsum[4];
    __shared__ int amLast;
    int lane = threadIdx.x & 63, wid = threadIdx.x >> 6;
    if (lane == 0) wsum[wid] = loss;
    __syncthreads();
    if (threadIdx.x == 0) {
        float partial = wsum[0] + wsum[1] + wsum[2] + wsum[3];
        __hip_atomic_store(&part[blockIdx.x], partial, __ATOMIC_RELEASE,
                           __HIP_MEMORY_SCOPE_AGENT);
        unsigned t = __hip_atomic_fetch_add(cnt, 1u, __ATOMIC_ACQ_REL,
                                            __HIP_MEMORY_SCOPE_AGENT);
        amLast = (t == (unsigned)(nb - 1));
    }
    __syncthreads();
    // ---- last-arriving block reduces all partials (agent-scope acquire) ----
    if (amLast) {
        float s = 0.0f;
        for (int t = threadIdx.x; t < nb; t += 256)
            s += __hip_atomic_load(&part[t], __ATOMIC_ACQUIRE,
                                   __HIP_MEMORY_SCOPE_AGENT);
#pragma unroll
        for (int off = 32; off > 0; off >>= 1)
            s += __shfl_down(s, off, 64);
        if (lane == 0) wsum[wid] = s;
        __syncthreads();
        if (threadIdx.x == 0)
            out[0] = wsum[0] + wsum[1] + wsum[2] + wsum[3];
    }
}

extern "C" void kernel_launch(void* const* d_in, const int* in_sizes, int n_in,
                              void* d_out, int out_size, void* d_ws, size_t ws_size,
                              hipStream_t stream) {
    const float* pred = (const float*)d_in[0];
    const float* tgt  = (const float*)d_in[1];
    const float* wgt  = (const float*)d_in[2];
    float* out = (float*)d_out;
    unsigned* cnt = (unsigned*)d_ws;                 // ticket counter (4 B)
    float* part = (float*)((char*)d_ws + 256);       // partials, own cacheline
    int n = in_sizes[2];

    int block = 256;
    int grid = (n + block - 1) / block;              // 977 for n=250000
    hipMemsetAsync(cnt, 0, sizeof(unsigned), stream);
    riou_loss_kernel<<<grid, block, 0, stream>>>(pred, tgt, wgt, cnt, part, out, n, grid);
}

// Round 12
// 75.342 us; speedup vs baseline: 1.2646x; 1.2646x over previous
//
#include <hip/hip_runtime.h>
#include <math.h>

// Rotated 3D IoU loss — round 12 = R10 two-kernel structure + ILP x2.
// R11 post-mortem: fused ticket-reduction with agent-scope atomics cost
// ~18us (per-block L2 writeback/invalidate on non-coherent XCD L2s) —
// reverted. R10 residual is in-wave dependency stall (occupancy-insensitive,
// R9/R10 A/B). Fix: TWO elements per thread in ONE basic block (index
// clamped, OOB masked via weight=0 — no branch, so the scheduler can
// interleave the two independent chains). Grid 489, launch_bounds(256,2)
// (the only config family w/o the allocator squeeze pathology).
// Semantics = literal emulation of the reference (incl. its u = -den_u/num
// "backward-extension" intersection mask — verified numerically in R6).

#define RCP(x) __builtin_amdgcn_rcpf(x)

#define ACC(M, X, Y) { sumx += (M) ? (X) : 0.0f; sumy += (M) ? (Y) : 0.0f; nv += (M) ? 1 : 0; }
#define PIB_B(MX, MY, M) { float amx = (MX) - c2x0, amy = (MY) - c2y0; \
        float pab = (abxB * amx + abyB * amy) * rabB; \
        float pdd = (adxB * amx + adyB * amy) * radB; \
        M = (fabsf(pab - 0.5f) < HT) & (fabsf(pdd - 0.5f) < HT); }
#define PIB_A(MX, MY, M) { float amx = (MX) - c1x0, amy = (MY) - c1y0; \
        float pab = (abxA * amx + abyA * amy) * rabA; \
        float pdd = (adxA * amx + adyA * amy) * radA; \
        M = (fabsf(pab - 0.5f) < HT) & (fabsf(pdd - 0.5f) < HT); }
#define ISECT(X1, Y1, X2, Y2, X3, Y3, X4, Y4, PX, PY, M) { \
        float ex = (X2) - (X1), ey = (Y2) - (Y1); \
        float fx = (X4) - (X3), fy = (Y4) - (Y3); \
        float gx = (X1) - (X3), gy = (Y1) - (Y3); \
        float num = fy * ex - fx * ey; \
        float dt_ = fx * gy - fy * gx; \
        float du_ = ex * gy - ey * gx; \
        float rr = RCP(num); \
        float tt = dt_ * rr, uu = -du_ * rr; \
        M = (fabsf(tt - 0.5f) < 0.5f) & (fabsf(uu - 0.5f) < 0.5f); \
        PX = (X1) + tt * ex; PY = (Y1) + tt * ey; }
#define SITEM(PX, PY, M, OX0, OY0, OX1, OY1, CNT) { \
        bool tk0 = (M) && ((CNT) == 0); bool tk1 = (M) && ((CNT) == 1); \
        OX0 = tk0 ? (PX) : OX0; OY0 = tk0 ? (PY) : OY0; \
        OX1 = tk1 ? (PX) : OX1; OY1 = tk1 ? (PY) : OY1; \
        CNT += (M) ? 1 : 0; }
#define EDGE_GROUP(X1, Y1, X2, Y2, EX0, EY0, EX1, EY1) { \
        int gc = 0; float px, py; bool mm; \
        ISECT(X1, Y1, X2, Y2, c2x0, c2y0, c2x1, c2y1, px, py, mm) \
        ACC(mm, px, py) SITEM(px, py, mm, EX0, EY0, EX1, EY1, gc) \
        ISECT(X1, Y1, X2, Y2, c2x1, c2y1, c2x2, c2y2, px, py, mm) \
        ACC(mm, px, py) SITEM(px, py, mm, EX0, EY0, EX1, EY1, gc) \
        ISECT(X1, Y1, X2, Y2, c2x2, c2y2, c2x3, c2y3, px, py, mm) \
        ACC(mm, px, py) SITEM(px, py, mm, EX0, EY0, EX1, EY1, gc) \
        ISECT(X1, Y1, X2, Y2, c2x3, c2y3, c2x0, c2y0, px, py, mm) \
        ACC(mm, px, py) SITEM(px, py, mm, EX0, EY0, EX1, EY1, gc) }
#define ANGPACK(K) { float xc = vx##K - mx_, yc = vy##K - my_; \
        float tt = xc * RCP(fmaxf(fabsf(xc) + fabsf(yc), 1e-38f)); \
        float key = copysignf(1.0f - tt, yc); \
        ang##K = m##K ? key : 1e6f; \
        pk##K = (__float_as_uint(xc) & 0xFFFF0000u) | (__float_as_uint(yc) >> 16); }
#define CE(A, B) { bool sw = ang##A > ang##B; \
        float mn = fminf(ang##A, ang##B), mx2 = fmaxf(ang##A, ang##B); \
        ang##A = mn; ang##B = mx2; \
        unsigned ta = pk##A; pk##A = sw ? pk##B : pk##A; pk##B = sw ? ta : pk##B; }
#define PAD(K) { pk##K = (ang##K > 5e5f) ? pk0 : pk##K; }
#define UPX(K) float ux##K = __uint_as_float(pk##K & 0xFFFF0000u); \
               float uy##K = __uint_as_float(pk##K << 16);
#define SHOE(A, B) cs += ux##A * uy##B - uy##A * ux##B;

__device__ __forceinline__ float riou_item(
    const float* __restrict__ pred, const float* __restrict__ tgt, float wg, int idx)
{
    const float* pp = pred + 7 * idx;
    const float* qq = tgt + 7 * idx;
    float p0 = pp[0], p1 = pp[1], p2 = pp[2], p3 = pp[3], p4 = pp[4], p5 = pp[5], p6 = pp[6];
    float q0 = qq[0], q1 = qq[1], q2 = qq[2], q3 = qq[3], q4 = qq[4], q5 = qq[5], q6 = qq[6];

    // ---- decode_fcos_obb (loc = 0) ----
    float w1 = p0 + p3, l1 = p1 + p4, h1 = p2 + p5;
    float oz1 = (p5 - p2) * 0.5f;
    float ox1 = (p3 - p0) * 0.5f, oy1 = (p4 - p1) * 0.5f;
    float sA = __sinf(p6), cA = __cosf(p6);
    float cx1 = ox1 * cA - oy1 * sA, cy1 = ox1 * sA + oy1 * cA;

    float w2 = q0 + q3, l2 = q1 + q4, h2 = q2 + q5;
    float oz2 = (q5 - q2) * 0.5f;
    float ox2 = (q3 - q0) * 0.5f, oy2 = (q4 - q1) * 0.5f;
    float sB = __sinf(q6), cB = __cosf(q6);
    float cx2 = ox2 * cB - oy2 * sB, cy2 = ox2 * sB + oy2 * cB;

    float vol1 = w1 * l1 * h1, vol2 = w2 * l2 * h2;
    float zo = fmaxf(fminf(oz1 + h1 * 0.5f, oz2 + h2 * 0.5f) -
                     fmaxf(oz1 - h1 * 0.5f, oz2 - h2 * 0.5f), 0.0f);

    // ---- corners: signs (+,+),(-,+),(-,-),(+,-) of (w/2, l/2), rotated ----
    float hw1 = 0.5f * w1, hl1 = 0.5f * l1;
    float c1x0 =  hw1 * cA - hl1 * sA + cx1, c1y0 =  hw1 * sA + hl1 * cA + cy1;
    float c1x1 = -hw1 * cA - hl1 * sA + cx1, c1y1 = -hw1 * sA + hl1 * cA + cy1;
    float c1x2 = -hw1 * cA + hl1 * sA + cx1, c1y2 = -hw1 * sA - hl1 * cA + cy1;
    float c1x3 =  hw1 * cA + hl1 * sA + cx1, c1y3 =  hw1 * sA - hl1 * cA + cy1;
    float hw2 = 0.5f * w2, hl2 = 0.5f * l2;
    float c2x0 =  hw2 * cB - hl2 * sB + cx2, c2y0 =  hw2 * sB + hl2 * cB + cy2;
    float c2x1 = -hw2 * cB - hl2 * sB + cx2, c2y1 = -hw2 * sB + hl2 * cB + cy2;
    float c2x2 = -hw2 * cB + hl2 * sB + cx2, c2y2 = -hw2 * sB - hl2 * cB + cy2;
    float c2x3 =  hw2 * cB + hl2 * sB + cx2, c2y3 =  hw2 * sB - hl2 * cB + cy2;

    float sumx = 0.0f, sumy = 0.0f;
    int nv = 0;

    // ---- point-in-box masks; x in (-tol,1+tol) <=> |x-0.5| < 0.5+tol ----
    const float HT = 0.5f + 1e-6f;
    float abxB = c2x1 - c2x0, abyB = c2y1 - c2y0;
    float adxB = c2x3 - c2x0, adyB = c2y3 - c2y0;
    float rabB = RCP(abxB * abxB + abyB * abyB);
    float radB = RCP(adxB * adxB + adyB * adyB);
    bool mA0, mA1, mA2, mA3;
    PIB_B(c1x0, c1y0, mA0) PIB_B(c1x1, c1y1, mA1)
    PIB_B(c1x2, c1y2, mA2) PIB_B(c1x3, c1y3, mA3)
    ACC(mA0, c1x0, c1y0) ACC(mA1, c1x1, c1y1) ACC(mA2, c1x2, c1y2) ACC(mA3, c1x3, c1y3)
    float abxA = c1x1 - c1x0, abyA = c1y1 - c1y0;
    float adxA = c1x3 - c1x0, adyA = c1y3 - c1y0;
    float rabA = RCP(abxA * abxA + abyA * abyA);
    float radA = RCP(adxA * adxA + adyA * adyA);
    bool mB0, mB1, mB2, mB3;
    PIB_A(c2x0, c2y0, mB0) PIB_A(c2x1, c2y1, mB1)
    PIB_A(c2x2, c2y2, mB2) PIB_A(c2x3, c2y3, mB3)
    ACC(mB0, c2x0, c2y0) ACC(mB1, c2x1, c2y1) ACC(mB2, c2x2, c2y2) ACC(mB3, c2x3, c2y3)

    // ---- edge-edge "intersections", reference's exact (buggy-u) mask ----
    float vx8 = 0.f, vy8 = 0.f, vx9 = 0.f, vy9 = 0.f;
    float vx10 = 0.f, vy10 = 0.f, vx11 = 0.f, vy11 = 0.f;
    float vx12 = 0.f, vy12 = 0.f, vx13 = 0.f, vy13 = 0.f;
    float vx14 = 0.f, vy14 = 0.f, vx15 = 0.f, vy15 = 0.f;
    int nv8_before = nv;
    EDGE_GROUP(c1x0, c1y0, c1x1, c1y1, vx8, vy8, vx9, vy9)
    int nv10_before = nv;
    EDGE_GROUP(c1x1, c1y1, c1x2, c1y2, vx10, vy10, vx11, vy11)
    int nv12_before = nv;
    EDGE_GROUP(c1x2, c1y2, c1x3, c1y3, vx12, vy12, vx13, vy13)
    int nv14_before = nv;
    EDGE_GROUP(c1x3, c1y3, c1x0, c1y0, vx14, vy14, vx15, vy15)
    bool m8  = (nv10_before - nv8_before) > 0, m9  = (nv10_before - nv8_before) > 1;
    bool m10 = (nv12_before - nv10_before) > 0, m11 = (nv12_before - nv10_before) > 1;
    bool m12 = (nv14_before - nv12_before) > 0, m13 = (nv14_before - nv12_before) > 1;
    bool m14 = (nv - nv14_before) > 0,          m15 = (nv - nv14_before) > 1;

    float vx0 = c1x0, vy0 = c1y0, vx1 = c1x1, vy1 = c1y1;
    float vx2 = c1x2, vy2 = c1y2, vx3 = c1x3, vy3 = c1y3;
    float vx4 = c2x0, vy4 = c2y0, vx5 = c2x1, vy5 = c2y1;
    float vx6 = c2x2, vy6 = c2y2, vx7 = c2x3, vy7 = c2y3;
    bool m0 = mA0, m1 = mA1, m2 = mA2, m3 = mA3;
    bool m4 = mB0, m5 = mB1, m6 = mB2, m7 = mB3;

    // ---- center; branch-free diamond key (monotone in atan2, verified) ----
    float inv_nv = RCP(fmaxf((float)nv, 1.0f));
    float mx_ = sumx * inv_nv, my_ = sumy * inv_nv;
    float ang0, ang1, ang2, ang3, ang4, ang5, ang6, ang7;
    float ang8, ang9, ang10, ang11, ang12, ang13, ang14, ang15;
    unsigned pk0, pk1, pk2, pk3, pk4, pk5, pk6, pk7;
    unsigned pk8, pk9, pk10, pk11, pk12, pk13, pk14, pk15;
    ANGPACK(0) ANGPACK(1) ANGPACK(2) ANGPACK(3)
    ANGPACK(4) ANGPACK(5) ANGPACK(6) ANGPACK(7)
    ANGPACK(8) ANGPACK(9) ANGPACK(10) ANGPACK(11)
    ANGPACK(12) ANGPACK(13) ANGPACK(14) ANGPACK(15)

    // ---- Batcher odd-even mergesort, 16 elems, 63 CEs; 5 inst/CE ----
    CE(0,1) CE(2,3) CE(4,5) CE(6,7) CE(8,9) CE(10,11) CE(12,13) CE(14,15)
    CE(0,2) CE(1,3) CE(4,6) CE(5,7) CE(8,10) CE(9,11) CE(12,14) CE(13,15)
    CE(1,2) CE(5,6) CE(9,10) CE(13,14)
    CE(0,4) CE(1,5) CE(2,6) CE(3,7) CE(8,12) CE(9,13) CE(10,14) CE(11,15)
    CE(2,4) CE(3,5) CE(10,12) CE(11,13)
    CE(1,2) CE(3,4) CE(5,6) CE(9,10) CE(11,12) CE(13,14)
    CE(0,8) CE(1,9) CE(2,10) CE(3,11) CE(4,12) CE(5,13) CE(6,14) CE(7,15)
    CE(4,8) CE(5,9) CE(6,10) CE(7,11)
    CE(2,4) CE(3,5) CE(6,8) CE(7,9) CE(10,12) CE(11,13)
    CE(1,2) CE(3,4) CE(5,6) CE(7,8) CE(9,10) CE(11,12) CE(13,14)

    // ---- ref padding: invalid slots (key 1e6) sorted last ----
    PAD(1) PAD(2) PAD(3) PAD(4) PAD(5) PAD(6) PAD(7) PAD(8)
    PAD(9) PAD(10) PAD(11) PAD(12) PAD(13) PAD(14) PAD(15)

    // ---- unpack + cyclic shoelace ----
    UPX(0) UPX(1) UPX(2) UPX(3) UPX(4) UPX(5) UPX(6) UPX(7)
    UPX(8) UPX(9) UPX(10) UPX(11) UPX(12) UPX(13) UPX(14) UPX(15)
    float cs = 0.0f;
    SHOE(0,1) SHOE(1,2) SHOE(2,3) SHOE(3,4) SHOE(4,5) SHOE(5,6) SHOE(6,7) SHOE(7,8)
    SHOE(8,9) SHOE(9,10) SHOE(10,11) SHOE(11,12) SHOE(12,13) SHOE(13,14) SHOE(14,15) SHOE(15,0)
    float inter = 0.5f * fabsf(cs);

    // ---- loss (iou2d*u2 cancels u2 -> inter3d = inter*zo) ----
    float inter3d = inter * zo;
    float u3d = vol1 + vol2 - inter3d;
    float iouf = (inter3d + 1.0f) * RCP(u3d + 1.0f);
    return -__logf(iouf) * wg;
}

__global__ __launch_bounds__(256, 2) void riou_loss_kernel(
    const float* __restrict__ pred, const float* __restrict__ tgt,
    const float* __restrict__ wgt, float* __restrict__ ws, int n)
{
    // two elements per thread, index-clamped (NO branch around the bodies:
    // both chains live in one basic block so the scheduler interleaves them)
    int i0 = blockIdx.x * 512 + threadIdx.x;
    int i1 = i0 + 256;
    int idx0 = min(i0, n - 1), idx1 = min(i1, n - 1);
    float wg0 = (i0 < n) ? wgt[idx0] : 0.0f;
    float wg1 = (i1 < n) ? wgt[idx1] : 0.0f;
    float loss = riou_item(pred, tgt, wg0, idx0)
               + riou_item(pred, tgt, wg1, idx1);

    // ---- block reduction -> ONE partial-sum store per block ----
#pragma unroll
    for (int off = 32; off > 0; off >>= 1)
        loss += __shfl_down(loss, off, 64);
    __shared__ float wsum[4];
    int lane = threadIdx.x & 63, wid = threadIdx.x >> 6;
    if (lane == 0) wsum[wid] = loss;
    __syncthreads();
    if (threadIdx.x == 0)
        ws[blockIdx.x] = wsum[0] + wsum[1] + wsum[2] + wsum[3];
}

__global__ __launch_bounds__(256) void riou_reduce_kernel(
    const float* __restrict__ ws, float* __restrict__ out, int nb)
{
    float s = 0.0f;
    for (int t = threadIdx.x; t < nb; t += 256) s += ws[t];
#pragma unroll
    for (int off = 32; off > 0; off >>= 1)
        s += __shfl_down(s, off, 64);
    __shared__ float wsum[4];
    int lane = threadIdx.x & 63, wid = threadIdx.x >> 6;
    if (lane == 0) wsum[wid] = s;
    __syncthreads();
    if (threadIdx.x == 0)
        out[0] = wsum[0] + wsum[1] + wsum[2] + wsum[3];
}

extern "C" void kernel_launch(void* const* d_in, const int* in_sizes, int n_in,
                              void* d_out, int out_size, void* d_ws, size_t ws_size,
                              hipStream_t stream) {
    const float* pred = (const float*)d_in[0];
    const float* tgt  = (const float*)d_in[1];
    const float* wgt  = (const float*)d_in[2];
    float* out = (float*)d_out;
    float* ws  = (float*)d_ws;
    int n = in_sizes[2];

    int grid = (n + 511) / 512;   // 489 for n=250000
    riou_loss_kernel<<<grid, 256, 0, stream>>>(pred, tgt, wgt, ws, n);
    riou_reduce_kernel<<<1, 256, 0, stream>>>(ws, out, grid);
}